// Round 11
// baseline (551.302 us; speedup 1.0000x reference)
//
#include <hip/hip_runtime.h>
#include <math.h>
#include <stdint.h>

#define Bb 512
#define Tt 512
#define Kk 128
#define NSTART 126   // K-2
#define NSTOP  127   // K-1
#define G 16         // chains per block
#define NBLK (Bb/G)  // 32 blocks
#define NTHR 256     // 4 waves

static constexpr float LOG2E = 1.4426950408889634f;
static constexpr float LN2   = 0.6931471805599453f;

typedef _Float16 f16x8 __attribute__((ext_vector_type(8)));
typedef float    f32x4 __attribute__((ext_vector_type(4)));

__device__ __forceinline__ float fexp2(float x){ return __builtin_amdgcn_exp2f(x); }
__device__ __forceinline__ float flog2(float x){ return __builtin_amdgcn_logf(x); }

// pack two f32 -> one dword of 2 fp16 (RNE via scalar casts)
__device__ __forceinline__ unsigned pkh(float lo, float hi){
  union { _Float16 h[2]; unsigned u; } p;
  p.h[0] = (_Float16)lo; p.h[1] = (_Float16)hi;
  return p.u;
}

// ============================================================================
// Block = 16 chains (cols), 4 waves. Linear-space CRF forward:
//   a_{t+1} = diag(exp feat_t) · E · a_t,  E = exp(trans) fp16.
// Per step: D[128 x 16] = E[128 x 128] x B[128 x 16] via 8 MFMA/wave
// (mfma_f32_16x16x32_f16). Wave w owns row-tiles 32w..32w+31 (Mtiles 2w,2w+1)
// = exactly K-tile w of the NEXT step's B operand.
//
// Fragment slot-map (free choice, must only be A/B-consistent):
//   slot (g = lane>>4, j) <-> k = 8g + j within a 32-K tile.
//   A-frag: lane (m = lane&15) elems = E[Mtile*16+m][kt*32+8g+j]
//   B-frag: lane (c = lane&15) elems = alpha[kt*32+8g+j][chain c]
// D (verified layout): col = lane&15 (chain), row = 4*(lane>>4)+reg.
//
// LDS B buffer layout [buf][ktile][slot 64][16B]: slot s = c + 16*q holds rows
// kt*32+8q..+7 of chain c as 8 fp16  =>  read = ds_read_b128 at l*16 (since
// c+16g == l, conflict-free);  write side: lane (c,g) mtile mt2 owns rows
// 32w+16mt2+4g+reg -> slot c+16*(2mt2+(g>>1)), dwords 2*(g&1)+{0,1} -> one
// coalesced ds_write_b64 per mtile.
//
// Renorm: exact per-chain max, written pre-barrier, consumed next step
// post-barrier in fp32 (one-step-late scale, target max -> 2^-6; fp16 holds
// one step of growth: typ 2^8..2^12, worst ~2^18 < 2^22 headroom).
// ============================================================================
__global__ __launch_bounds__(NTHR) void crf_mfma(
    const float* __restrict__ feats,   // [B,T,K]
    const int*   __restrict__ tags,    // [B,T]
    const float* __restrict__ trans,   // [K,K] trans[next, prev]
    float* __restrict__ part)          // [B]
{
  const int tid = threadIdx.x;
  const int w   = tid >> 6;     // wave 0..3
  const int l   = tid & 63;     // lane
  const int c   = l & 15;       // chain col / A m-index
  const int g   = l >> 4;       // 0..3
  const int B0  = blockIdx.x * G;

  __shared__ __align__(16) unsigned bufU[2][4][64][4];  // 8 KB, double-buffered
  __shared__ float Mp[2][4][G];                         // per-wave chain maxes
  __shared__ float fwdS[G];
  __shared__ float gpart[G][17];

  // ---- E fragments: E[mt2][kt] = exp(trans) fp16, resident (32 VGPR) ----
  f16x8 E[2][4];
  #pragma unroll
  for (int mt2 = 0; mt2 < 2; ++mt2) {
    const int mrow = 32*w + 16*mt2 + c;
    #pragma unroll
    for (int kt = 0; kt < 4; ++kt) {
      const float* tr = trans + (size_t)mrow * Kk + kt*32 + g*8;
      float4 v0 = *reinterpret_cast<const float4*>(tr);
      float4 v1 = *reinterpret_cast<const float4*>(tr + 4);
      E[mt2][kt][0] = (_Float16)fexp2(v0.x * LOG2E);
      E[mt2][kt][1] = (_Float16)fexp2(v0.y * LOG2E);
      E[mt2][kt][2] = (_Float16)fexp2(v0.z * LOG2E);
      E[mt2][kt][3] = (_Float16)fexp2(v0.w * LOG2E);
      E[mt2][kt][4] = (_Float16)fexp2(v1.x * LOG2E);
      E[mt2][kt][5] = (_Float16)fexp2(v1.y * LOG2E);
      E[mt2][kt][6] = (_Float16)fexp2(v1.z * LOG2E);
      E[mt2][kt][7] = (_Float16)fexp2(v1.w * LOG2E);
    }
  }

  // ---- init buf0 with alpha0 = one-hot(START), via the standard write path ----
  #pragma unroll
  for (int mt2 = 0; mt2 < 2; ++mt2) {
    float y[4];
    #pragma unroll
    for (int reg = 0; reg < 4; ++reg)
      y[reg] = (32*w + 16*mt2 + 4*g + reg == NSTART) ? 1.0f : 0.0f;
    unsigned* dst = &bufU[0][w][c + 16*(2*mt2 + (g>>1))][2*(g&1)];
    *reinterpret_cast<uint2*>(dst) = make_uint2(pkh(y[0], y[1]), pkh(y[2], y[3]));
  }
  if (l < G) Mp[0][w][l] = (w == 3) ? 1.0f : 0.0f;  // wave-partial max of b0

  // ---- feats prefetch ring (2 steps deep) ----
  const float* fb = feats + (size_t)(B0 + c) * Tt * Kk + 32*w + 4*g;
  float4 F[2][2];
  F[0][0] = *reinterpret_cast<const float4*>(fb);
  F[0][1] = *reinterpret_cast<const float4*>(fb + 16);
  F[1][0] = *reinterpret_cast<const float4*>(fb + Kk);
  F[1][1] = *reinterpret_cast<const float4*>(fb + Kk + 16);

  float C2 = 0.0f;   // per-chain log2 scale accumulator (uniform across lanes of same c)
  __syncthreads();

  for (int t = 0; t < Tt; ++t) {
    const int cur = t & 1, nxt = cur ^ 1;

    // B fragments: 4 x ds_read_b128 (conflict-free)
    f16x8 Bf[4];
    #pragma unroll
    for (int kt = 0; kt < 4; ++kt) {
      union { uint4 u; f16x8 h; } cv;
      cv.u = *reinterpret_cast<const uint4*>(&bufU[cur][kt][l][0]);
      Bf[kt] = cv.h;
    }
    // per-chain max from last step (exact, one-step-late application)
    const float Mmax = fmaxf(fmaxf(Mp[cur][0][c], Mp[cur][1][c]),
                             fmaxf(Mp[cur][2][c], Mp[cur][3][c]));
    const float lm  = flog2(Mmax);
    const float lsc = -6.0f - lm;
    C2 += lm + 6.0f;

    // MFMA: D = E * b   (two Mtiles, K-loop of 4)
    f32x4 acc0 = {0.f, 0.f, 0.f, 0.f}, acc1 = {0.f, 0.f, 0.f, 0.f};
    #pragma unroll
    for (int kt = 0; kt < 4; ++kt) {
      acc0 = __builtin_amdgcn_mfma_f32_16x16x32_f16(E[0][kt], Bf[kt], acc0, 0, 0, 0);
      acc1 = __builtin_amdgcn_mfma_f32_16x16x32_f16(E[1][kt], Bf[kt], acc1, 0, 0, 0);
    }

    // feats for this step + prefetch t+2
    const float4 f0 = F[cur][0], f1 = F[cur][1];
    {
      int tn = t + 2; if (tn > Tt - 1) tn = Tt - 1;
      F[cur][0] = *reinterpret_cast<const float4*>(fb + (size_t)tn * Kk);
      F[cur][1] = *reinterpret_cast<const float4*>(fb + (size_t)tn * Kk + 16);
    }

    // y = D * exp(feat) * 2^lsc   (fold scale into exp2 argument)
    float y0[4], y1[4];
    const float fr0[4] = {f0.x, f0.y, f0.z, f0.w};
    const float fr1[4] = {f1.x, f1.y, f1.z, f1.w};
    #pragma unroll
    for (int reg = 0; reg < 4; ++reg) {
      y0[reg] = acc0[reg] * fexp2(fmaf(fr0[reg], LOG2E, lsc));
      y1[reg] = acc1[reg] * fexp2(fmaf(fr1[reg], LOG2E, lsc));
    }

    // new per-chain wave-partial max (reduce over this lane's 8 rows, then g)
    float pm = fmaxf(fmaxf(fmaxf(y0[0], y0[1]), fmaxf(y0[2], y0[3])),
                     fmaxf(fmaxf(y1[0], y1[1]), fmaxf(y1[2], y1[3])));
    pm = fmaxf(pm, __shfl_xor(pm, 16, 64));
    pm = fmaxf(pm, __shfl_xor(pm, 32, 64));
    if (l < G) Mp[nxt][w][l] = pm;

    // pack + write next B operand (2 x ds_write_b64, coalesced)
    #pragma unroll
    for (int mt2 = 0; mt2 < 2; ++mt2) {
      const float* y = (mt2 == 0) ? y0 : y1;
      unsigned* dst = &bufU[nxt][w][c + 16*(2*mt2 + (g>>1))][2*(g&1)];
      *reinterpret_cast<uint2*>(dst) = make_uint2(pkh(y[0], y[1]), pkh(y[2], y[3]));
    }
    __syncthreads();
  }

  // ---- forward score: fwd_c = ln2*(C2 + log2( sum_n b_T[n,c] * e^{T[STOP,n]} )) ----
  {
    float v = 0.0f;
    #pragma unroll
    for (int kt = 0; kt < 4; ++kt) {
      union { uint4 u; f16x8 h; } cv;
      cv.u = *reinterpret_cast<const uint4*>(&bufU[0][kt][l][0]);   // Tt even -> buf0
      const float* ts = trans + (size_t)NSTOP * Kk + kt*32 + g*8;
      float4 s0 = *reinterpret_cast<const float4*>(ts);
      float4 s1 = *reinterpret_cast<const float4*>(ts + 4);
      const float sv[8] = {s0.x, s0.y, s0.z, s0.w, s1.x, s1.y, s1.z, s1.w};
      #pragma unroll
      for (int j = 0; j < 8; ++j)
        v = fmaf((float)cv.h[j], fexp2(sv[j] * LOG2E), v);
    }
    v += __shfl_xor(v, 16, 64);
    v += __shfl_xor(v, 32, 64);
    const float fwd = LN2 * (C2 + flog2(v));
    if (w == 0 && l < G) fwdS[l] = fwd;
  }
  __syncthreads();

  // ---- gold path score: thread (c2, seg) covers 32 timesteps of chain c2 ----
  {
    const int c2  = tid & 15;
    const int seg = tid >> 4;            // 0..15
    const int bc  = B0 + c2;
    const int* tg = tags + (size_t)bc * Tt;
    const float* fbase = feats + (size_t)bc * Tt * Kk;
    const int t0 = seg * 32;
    int prev = (t0 == 0) ? NSTART : tg[t0 - 1];
    float gg = 0.0f;
    for (int tt = t0; tt < t0 + 32; ++tt) {
      const int curt = tg[tt];
      gg += trans[(size_t)curt * Kk + prev] + fbase[(size_t)tt * Kk + curt];
      prev = curt;
    }
    if (seg == 15) gg += trans[(size_t)NSTOP * Kk + tg[Tt - 1]];
    gpart[c2][seg] = gg;
  }
  __syncthreads();
  if (tid < G) {
    float gold = 0.0f;
    #pragma unroll
    for (int s = 0; s < 16; ++s) gold += gpart[tid][s];
    part[B0 + tid] = fwdS[tid] - gold;
  }
}

__global__ __launch_bounds__(256) void reduce_mean_kernel(
    const float* __restrict__ part, float* __restrict__ out)
{
  __shared__ float buf[4];
  const int tid = threadIdx.x;
  float v = part[tid] + part[tid + 256];
  #pragma unroll
  for (int off = 32; off >= 1; off >>= 1) v += __shfl_xor(v, off, 64);
  if ((tid & 63) == 0) buf[tid >> 6] = v;
  __syncthreads();
  if (tid == 0)
    out[0] = (buf[0] + buf[1] + buf[2] + buf[3]) * (1.0f / (float)Bb);
}

extern "C" void kernel_launch(void* const* d_in, const int* in_sizes, int n_in,
                              void* d_out, int out_size, void* d_ws, size_t ws_size,
                              hipStream_t stream) {
  const float* feats = (const float*)d_in[0];
  const int*   tags  = (const int*)d_in[1];
  const float* trans = (const float*)d_in[2];
  float* part = (float*)d_ws;

  crf_mfma<<<dim3(NBLK), dim3(NTHR), 0, stream>>>(feats, tags, trans, part);
  reduce_mean_kernel<<<dim3(1), dim3(256), 0, stream>>>(part, (float*)d_out);
}

// Round 12
// 543.846 us; speedup vs baseline: 1.0137x; 1.0137x over previous
//
#include <hip/hip_runtime.h>
#include <math.h>

#define Bb 512
#define Tt 512
#define Kk 128
#define NSTART 126   // K-2
#define NSTOP  127   // K-1
#define G 16         // chains per wave (MFMA N)
#define NBLK (Bb/G)  // 32 blocks x 1 wave

static constexpr float LOG2E = 1.4426950408889634f;
static constexpr float LN2   = 0.6931471805599453f;

typedef _Float16 f16x8 __attribute__((ext_vector_type(8)));
typedef float    f32x4 __attribute__((ext_vector_type(4)));

__device__ __forceinline__ float fexp2(float x){ return __builtin_amdgcn_exp2f(x); }
__device__ __forceinline__ float flog2(float x){ return __builtin_amdgcn_logf(x); }

// pack two f32 -> one dword of 2 fp16, RNE (r11-verified numerics)
__device__ __forceinline__ unsigned pkh(float lo, float hi){
  union { _Float16 h[2]; unsigned u; } p;
  p.h[0] = (_Float16)lo; p.h[1] = (_Float16)hi;
  return p.u;
}

// ============================================================================
// One wave = 16 chains, fully in registers. Linear-space CRF forward:
//   a_{t+1} = diag(exp feat_t) . E . a_t,   E = exp(trans) fp16 (RNE).
// Per step: D[128x16] = E[128x128] x B[128x16] as 8 Mtiles x 4 ktiles of
// mfma_f32_16x16x32_f16. Slot map (A/B-consistent, free choice per r11):
//   ktile kt, lane group g, slot j  <->  state 32kt + 4g + (j&3) + 16*(j>>2)
// With this map, D (row = 16mt + 4g + reg, col = c = lane&15) feeds the next
// step's B-fragment IN-LANE: B[kt] slots = {acc[2kt][0..3], acc[2kt+1][0..3]}.
// => no LDS, no barriers, no cross-lane ops in the loop except the renorm max
// (2 shfl_xor, one-step-late => off critical path).
// Renorm (r11-exact): per-chain max -> 2^-6 target, scale folded into the
// exp2(feat) argument; C2 accumulates log2 scales. fp16 headroom: one-step
// growth <= 128*e^9*2^-6 ~ 2^14 < 2^16 max; floor 2^-18 rel (invisible).
// ============================================================================
__global__ __attribute__((amdgpu_flat_work_group_size(64, 64),
                          amdgpu_waves_per_eu(1, 1)))
void crf_wave_mfma(
    const float* __restrict__ feats,   // [B,T,K]
    const int*   __restrict__ tags,    // [B,T]
    const float* __restrict__ trans,   // [K,K] trans[next, prev]
    float* __restrict__ part)          // [B]
{
  const int l  = threadIdx.x;   // 0..63
  const int c  = l & 15;        // chain col / m row index
  const int g  = l >> 4;        // 0..3
  const int B0 = blockIdx.x * G;

  // ---- E A-fragments (fp16 RNE), 128 VGPR/AGPR: E[mt][kt] slot j =
  //      exp(trans[16mt + c][32kt + 4g + (j&3) + 16*(j>>2)]) ----
  f16x8 E[8][4];
  #pragma unroll
  for (int mt = 0; mt < 8; ++mt) {
    const float* tr = trans + (size_t)(16*mt + c) * Kk + 4*g;
    #pragma unroll
    for (int kt = 0; kt < 4; ++kt) {
      float4 v0 = *reinterpret_cast<const float4*>(tr + 32*kt);        // j=0..3
      float4 v1 = *reinterpret_cast<const float4*>(tr + 32*kt + 16);   // j=4..7
      f16x8 e;
      e[0] = (_Float16)fexp2(v0.x * LOG2E);
      e[1] = (_Float16)fexp2(v0.y * LOG2E);
      e[2] = (_Float16)fexp2(v0.z * LOG2E);
      e[3] = (_Float16)fexp2(v0.w * LOG2E);
      e[4] = (_Float16)fexp2(v1.x * LOG2E);
      e[5] = (_Float16)fexp2(v1.y * LOG2E);
      e[6] = (_Float16)fexp2(v1.z * LOG2E);
      e[7] = (_Float16)fexp2(v1.w * LOG2E);
      E[mt][kt] = e;
    }
  }

  // ---- B-frag init: alpha0 one-hot at state 126 = kt3, g3, slot6 ----
  f16x8 Bf[4];
  #pragma unroll
  for (int kt = 0; kt < 4; ++kt) Bf[kt] = (f16x8)(_Float16)0.0f;
  if (g == 3) Bf[3][6] = (_Float16)1.0f;

  // ---- feats: lane reads rows 16mt+4g..+3 of chain B0+c; 2-step ring ----
  const float* fb = feats + (size_t)(B0 + c) * Tt * Kk + 4*g;
  float4 FA[8], FB[8];
  #pragma unroll
  for (int mt = 0; mt < 8; ++mt) {
    FA[mt] = *reinterpret_cast<const float4*>(fb + 16*mt);
    FB[mt] = *reinterpret_cast<const float4*>(fb + Kk + 16*mt);
  }

  float C2 = 0.0f;       // per-chain accumulated log2 scale
  float pmprev = 1.0f;   // previous step's per-chain max (packed domain)

#define STEP(FC, TT)                                                           \
  {                                                                            \
    f32x4 acc[8];                                                              \
    _Pragma("unroll") for (int mt = 0; mt < 8; ++mt)                           \
      acc[mt] = (f32x4){0.f, 0.f, 0.f, 0.f};                                   \
    _Pragma("unroll") for (int kt = 0; kt < 4; ++kt) {                         \
      _Pragma("unroll") for (int mt = 0; mt < 8; ++mt)                         \
        acc[mt] = __builtin_amdgcn_mfma_f32_16x16x32_f16(E[mt][kt], Bf[kt],    \
                                                         acc[mt], 0, 0, 0);    \
    }                                                                          \
    const float lm  = flog2(pmprev);     /* prev-step max: slack hides shfl */ \
    C2 += lm + 6.0f;                                                           \
    const float lsc = -6.0f - lm;                                              \
    float y[8][4]; float pm = 0.0f;                                            \
    _Pragma("unroll") for (int mt = 0; mt < 8; ++mt) {                         \
      const float fr[4] = {FC[mt].x, FC[mt].y, FC[mt].z, FC[mt].w};            \
      _Pragma("unroll") for (int r = 0; r < 4; ++r) {                          \
        y[mt][r] = acc[mt][r] * fexp2(fmaf(fr[r], LOG2E, lsc));                \
        pm = fmaxf(pm, y[mt][r]);                                              \
      }                                                                        \
    }                                                                          \
    { int tn = (TT) + 2; if (tn > Tt - 1) tn = Tt - 1;                         \
      const float* fp = fb + (size_t)tn * Kk;                                  \
      _Pragma("unroll") for (int mt = 0; mt < 8; ++mt)                         \
        FC[mt] = *reinterpret_cast<const float4*>(fp + 16*mt); }               \
    _Pragma("unroll") for (int kt = 0; kt < 4; ++kt) {                         \
      union { unsigned u[4]; f16x8 h; } bb;                                    \
      bb.u[0] = pkh(y[2*kt][0],   y[2*kt][1]);                                 \
      bb.u[1] = pkh(y[2*kt][2],   y[2*kt][3]);                                 \
      bb.u[2] = pkh(y[2*kt+1][0], y[2*kt+1][1]);                               \
      bb.u[3] = pkh(y[2*kt+1][2], y[2*kt+1][3]);                               \
      Bf[kt] = bb.h;                                                           \
    }                                                                          \
    pm = fmaxf(pm, __shfl_xor(pm, 16, 64));                                    \
    pm = fmaxf(pm, __shfl_xor(pm, 32, 64));                                    \
    pmprev = pm;                                                               \
  }

  for (int t = 0; t < Tt; t += 2) {
    STEP(FA, t)
    STEP(FB, t + 1)
  }
#undef STEP

  // ---- forward score: fwd_c = ln2*(C2 + log2 sum_k B[k][c]*e^{T[STOP,k]}) ----
  float fwd;
  {
    const float* ts = trans + (size_t)NSTOP * Kk + 4*g;
    float v = 0.0f;
    #pragma unroll
    for (int kt = 0; kt < 4; ++kt) {
      float4 s0 = *reinterpret_cast<const float4*>(ts + 32*kt);
      float4 s1 = *reinterpret_cast<const float4*>(ts + 32*kt + 16);
      const float sv[8] = {s0.x, s0.y, s0.z, s0.w, s1.x, s1.y, s1.z, s1.w};
      #pragma unroll
      for (int j = 0; j < 8; ++j)
        v = fmaf((float)Bf[kt][j], fexp2(sv[j] * LOG2E), v);
    }
    v += __shfl_xor(v, 16, 64);
    v += __shfl_xor(v, 32, 64);
    fwd = LN2 * (C2 + flog2(v));
  }

  // ---- gold path: lane (c2 = l&15, seg = l>>4) does 128 timesteps ----
  {
    const int c2  = l & 15;
    const int seg = l >> 4;
    const int bc  = B0 + c2;
    const int* tg = tags + (size_t)bc * Tt;
    const float* fbase = feats + (size_t)bc * Tt * Kk;
    const int t0 = seg * 128;
    int prev = (t0 == 0) ? NSTART : tg[t0 - 1];
    float gg = 0.0f;
    for (int tt = t0; tt < t0 + 128; ++tt) {
      const int cur = tg[tt];
      gg += trans[(size_t)cur * Kk + prev] + fbase[(size_t)tt * Kk + cur];
      prev = cur;
    }
    if (seg == 3) gg += trans[(size_t)NSTOP * Kk + tg[Tt - 1]];
    gg += __shfl_xor(gg, 16, 64);
    gg += __shfl_xor(gg, 32, 64);

    if (l < G) part[B0 + l] = fwd - gg;   // l<16 => c=l, g=0: has chain-l C2/fwd/gold
  }
}

__global__ __launch_bounds__(256) void reduce_mean_kernel(
    const float* __restrict__ part, float* __restrict__ out)
{
  __shared__ float buf[4];
  const int tid = threadIdx.x;
  float v = part[tid] + part[tid + 256];
  #pragma unroll
  for (int off = 32; off >= 1; off >>= 1) v += __shfl_xor(v, off, 64);
  if ((tid & 63) == 0) buf[tid >> 6] = v;
  __syncthreads();
  if (tid == 0)
    out[0] = (buf[0] + buf[1] + buf[2] + buf[3]) * (1.0f / (float)Bb);
}

extern "C" void kernel_launch(void* const* d_in, const int* in_sizes, int n_in,
                              void* d_out, int out_size, void* d_ws, size_t ws_size,
                              hipStream_t stream) {
  const float* feats = (const float*)d_in[0];
  const int*   tags  = (const int*)d_in[1];
  const float* trans = (const float*)d_in[2];
  float* part = (float*)d_ws;

  crf_wave_mfma<<<dim3(NBLK), dim3(64), 0, stream>>>(feats, tags, trans, part);
  reduce_mean_kernel<<<dim3(1), dim3(256), 0, stream>>>(part, (float*)d_out);
}

// Round 13
// 266.879 us; speedup vs baseline: 2.0657x; 2.0378x over previous
//
#include <hip/hip_runtime.h>
#include <math.h>

#define Bb 512
#define Tt 512
#define Kk 128
#define NSTART 126   // K-2
#define NSTOP  127   // K-1
#define NTHR 256     // 4 waves, one block per chain

static constexpr float LOG2E = 1.4426950408889634f;
static constexpr float LN2   = 0.6931471805599453f;

__device__ __forceinline__ float fexp2(float x){ return __builtin_amdgcn_exp2f(x); }
__device__ __forceinline__ float flog2(float x){ return __builtin_amdgcn_logf(x); }

// acc += e.lo*a.lo + e.hi*a.hi  (packed fp16, fp32 accumulate)
__device__ __forceinline__ void dot2a(float& acc, unsigned e, unsigned a){
  asm("v_dot2_f32_f16 %0, %1, %2, %0" : "+v"(acc) : "v"(e), "v"(a));
}
// pack two f32 -> dword of 2 fp16, RNE (r11/r12-verified numerics)
__device__ __forceinline__ unsigned pkh(float lo, float hi){
  union { _Float16 h[2]; unsigned u; } p;
  p.h[0] = (_Float16)lo; p.h[1] = (_Float16)hi;
  return p.u;
}
__device__ __forceinline__ float cvth(unsigned u){
  float f; asm("v_cvt_f32_f16 %0, %1" : "=v"(f) : "v"(u)); return f;
}
template<int CTRL>
__device__ __forceinline__ float dpp_mov(float s){
  union {float f; int i;} a, r; a.f = s;
  r.i = __builtin_amdgcn_update_dpp(a.i, a.i, CTRL, 0xf, 0xf, false);
  return r.f;
}
#define QP_XOR1  0xB1    // quad_perm [1,0,3,2]
#define QP_XOR2  0x4E    // quad_perm [2,3,0,1]
#define ROW_ROR4 0x124   // row_ror:4
#define ROW_ROR8 0x128   // row_ror:8

// ============================================================================
// One block per chain; 256 threads: q = tid&3 (prev-slice), nb = tid>>2 ->
// thread produces next rows {nb, nb+64}. Linear-space CRF forward:
//   a_{t+1} = diag(exp feat_t) . E . a_t,  E = exp(trans) fp16 RNE.
// Alpha in LDS, fp16 INTERLEAVED pairs: dword d = states (d lo, d+64 hi),
// double-buffered; thread q reads dwords 16q..16q+15 (4 x ds_read_b128,
// 4 distinct addrs/instr, 2-way bank alias = free). E pairs matched to that
// layout in 32 VGPRs. Writer: single predicated ds_write_b32 (q==0 lane
// writes dword nb = pkh(y_nb, y_{nb+64})).
// Renorm: EXACT one-step-late (r12): block max of packed y written to
// Mp[nxt] pre-barrier, consumed next step as 2^{-6-lm} folded into the
// exp2(feat) argument; C2 accumulates applied log2 scales. fp16 headroom:
// packed max 2^-6 x one-step growth <= 2^15.4 < 65504.
// amdgpu_waves_per_eu(2,2): exact occupancy -> full 256-VGPR budget -> the
// E array stays in arch VGPRs (r7's 32 accvgpr_read/step tax removed).
// ============================================================================
__global__ __attribute__((amdgpu_flat_work_group_size(NTHR, NTHR),
                          amdgpu_waves_per_eu(2, 2)))
void crf_v13(
    const float* __restrict__ feats,   // [B,T,K]
    const int*   __restrict__ tags,    // [B,T]
    const float* __restrict__ trans,   // [K,K] trans[next, prev]
    float* __restrict__ part)          // [B]
{
  const int b   = blockIdx.x;
  const int tid = threadIdx.x;
  const int q   = tid & 3;
  const int nb  = tid >> 2;     // 0..63
  const int w   = tid >> 6;     // wave 0..3
  const int l   = tid & 63;

  __shared__ __align__(16) unsigned aW[2][64];  // fp16 pairs (d, d+64)
  __shared__ __align__(16) float Mp[2][4];      // per-wave packed-y maxes
  __shared__ float red[4];

  // ---- E pairs in VGPRs: E0[j] = {E[nb][16q+j], E[nb][16q+j+64]},
  //      E1[j] same for row nb+64 ----
  unsigned E0[16], E1[16];
  {
    const float* t0 = trans + (size_t)nb * Kk;
    const float* t1 = trans + (size_t)(nb + 64) * Kk;
    #pragma unroll
    for (int j = 0; j < 16; ++j) {
      const int d = 16*q + j;
      E0[j] = pkh(fexp2(t0[d] * LOG2E), fexp2(t0[d + 64] * LOG2E));
      E1[j] = pkh(fexp2(t1[d] * LOG2E), fexp2(t1[d + 64] * LOG2E));
    }
  }
  #pragma unroll
  for (int j = 0; j < 16; ++j)
    asm volatile("" : "+v"(E0[j]), "+v"(E1[j]));

  // ---- init: alpha0 one-hot at state 126 = dword 62 HIGH half; Mp=1 ----
  if (tid < 64) aW[0][tid] = (tid == 62) ? 0x3C000000u : 0u;  // fp16 1.0 hi
  if (tid < 4)  Mp[0][tid] = 1.0f;
  __syncthreads();

  const float* fb = feats + (size_t)b * Tt * Kk;
  float f0  = fb[nb],       f1  = fb[nb + 64];        // t = 0
  float f0n = fb[Kk + nb],  f1n = fb[Kk + nb + 64];   // t = 1
  float C2 = 0.0f;

  for (int t = 0; t < Tt; ++t) {
    const int cur = t & 1, nxt = cur ^ 1;

    // prev-step block max -> scale for this step (one-step-late, exact)
    const float4 mp4 = *reinterpret_cast<const float4*>(&Mp[cur][0]);
    const float mm = fmaxf(fmaxf(mp4.x, mp4.y), fmaxf(mp4.z, mp4.w));
    const float lm = flog2(mm);
    C2 += lm + 6.0f;
    const float lsc = -6.0f - lm;

    // this thread's 32 prev states: 4 b128 broadcast reads
    const uint4* ap = reinterpret_cast<const uint4*>(&aW[cur][16 * q]);
    uint4 av0 = ap[0], av1 = ap[1], av2 = ap[2], av3 = ap[3];

    float A0=0.f,A1=0.f,A2=0.f,A3=0.f, C0=0.f,C1=0.f,C2_=0.f,C3=0.f;
#define D4(AV, J)                                              \
    dot2a(A0, E0[J+0], AV.x);  dot2a(C0, E1[J+0], AV.x);       \
    dot2a(A1, E0[J+1], AV.y);  dot2a(C1, E1[J+1], AV.y);       \
    dot2a(A2, E0[J+2], AV.z);  dot2a(C2_, E1[J+2], AV.z);      \
    dot2a(A3, E0[J+3], AV.w);  dot2a(C3, E1[J+3], AV.w);
    D4(av0, 0) D4(av1, 4) D4(av2, 8) D4(av3, 12)
#undef D4
    float s0 = (A0 + A1) + (A2 + A3);
    float s1 = (C0 + C1) + (C2_ + C3);
    s0 = s0 + dpp_mov<QP_XOR1>(s0);   // combine the 4 q-partials (VALU DPP)
    s0 = s0 + dpp_mov<QP_XOR2>(s0);
    s1 = s1 + dpp_mov<QP_XOR1>(s1);
    s1 = s1 + dpp_mov<QP_XOR2>(s1);

    const float y0 = s0 * fexp2(fmaf(f0, LOG2E, lsc));
    const float y1 = s1 * fexp2(fmaf(f1, LOG2E, lsc));

    // feats ring: consume, shift, prefetch t+2
    f0 = f0n; f1 = f1n;
    {
      int tn = t + 2; if (tn > Tt - 1) tn = Tt - 1;
      f0n = fb[(size_t)tn * Kk + nb];
      f1n = fb[(size_t)tn * Kk + nb + 64];
    }

    // wave-partial max of packed y (y quad-uniform -> DPP row reduce + 2 shfl)
    float pm = fmaxf(y0, y1);
    pm = fmaxf(pm, dpp_mov<ROW_ROR4>(pm));
    pm = fmaxf(pm, dpp_mov<ROW_ROR8>(pm));
    pm = fmaxf(pm, __shfl_xor(pm, 16, 64));
    pm = fmaxf(pm, __shfl_xor(pm, 32, 64));
    if (l == 0) Mp[nxt][w] = pm;

    // write next alpha: one predicated b32 (dword nb = rows nb, nb+64)
    if (q == 0) aW[nxt][nb] = pkh(y0, y1);
    __syncthreads();
  }

  // ---- forward score: fwd = ln2*(C2 + log2 sum_s a[s]*e^{T[STOP,s]}) ----
  float v = 0.0f;
  if (tid < 64) {                      // final alpha in buf0 (Tt even)
    const unsigned d = aW[0][tid];
    v = cvth(d)       * fexp2(trans[(size_t)NSTOP * Kk + tid]      * LOG2E)
      + cvth(d >> 16) * fexp2(trans[(size_t)NSTOP * Kk + tid + 64] * LOG2E);
  }
  #pragma unroll
  for (int off = 32; off >= 1; off >>= 1) v += __shfl_xor(v, off, 64);
  if (l == 0) red[w] = v;
  __syncthreads();
  const float S = (red[0] + red[1]) + (red[2] + red[3]);
  const float fwd = LN2 * (C2 + flog2(S));

  // ---- gold path score (2 timesteps per thread; exact fp32) ----
  __syncthreads();                     // red reuse guard
  const int* tg = tags + (size_t)b * Tt;
  float g = 0.0f;
  #pragma unroll
  for (int k2 = 0; k2 < Tt / NTHR; ++k2) {
    const int tt   = tid + k2 * NTHR;
    const int curt = tg[tt];
    const int prv  = (tt == 0) ? NSTART : tg[tt - 1];
    g += trans[(size_t)curt * Kk + prv] + fb[(size_t)tt * Kk + curt];
  }
  if (tid == 0) g += trans[(size_t)NSTOP * Kk + tg[Tt - 1]];
  #pragma unroll
  for (int off = 32; off >= 1; off >>= 1) g += __shfl_xor(g, off, 64);
  if (l == 0) red[w] = g;
  __syncthreads();
  const float gold = (red[0] + red[1]) + (red[2] + red[3]);

  if (tid == 0) part[b] = fwd - gold;
}

__global__ __launch_bounds__(256) void reduce_mean_kernel(
    const float* __restrict__ part, float* __restrict__ out)
{
  __shared__ float buf[4];
  const int tid = threadIdx.x;
  float v = part[tid] + part[tid + 256];
  #pragma unroll
  for (int off = 32; off >= 1; off >>= 1) v += __shfl_xor(v, off, 64);
  if ((tid & 63) == 0) buf[tid >> 6] = v;
  __syncthreads();
  if (tid == 0)
    out[0] = (buf[0] + buf[1] + buf[2] + buf[3]) * (1.0f / (float)Bb);
}

extern "C" void kernel_launch(void* const* d_in, const int* in_sizes, int n_in,
                              void* d_out, int out_size, void* d_ws, size_t ws_size,
                              hipStream_t stream) {
  const float* feats = (const float*)d_in[0];
  const int*   tags  = (const int*)d_in[1];
  const float* trans = (const float*)d_in[2];
  float* part = (float*)d_ws;

  crf_v13<<<dim3(Bb), dim3(NTHR), 0, stream>>>(feats, tags, trans, part);
  reduce_mean_kernel<<<dim3(1), dim3(256), 0, stream>>>(part, (float*)d_out);
}

// Round 14
// 254.284 us; speedup vs baseline: 2.1681x; 1.0495x over previous
//
#include <hip/hip_runtime.h>
#include <math.h>

#define Bb 512
#define Tt 512
#define Kk 128
#define NSTART 126   // K-2
#define NSTOP  127   // K-1
#define NTHR 256     // threads per block (4 waves), one block per batch chain
#define PW 32        // prev states per thread (quarter)

static constexpr float LOG2E = 1.4426950408889634f;
static constexpr float LN2   = 0.6931471805599453f;

__device__ __forceinline__ float fexp2(float x) { return __builtin_amdgcn_exp2f(x); }
__device__ __forceinline__ float flog2(float x) { return __builtin_amdgcn_logf(x); }
__device__ __forceinline__ float frcp (float x) { return __builtin_amdgcn_rcpf(x); }

// packed-bf16 dot2: d = a.lo*b.lo + a.hi*b.hi + c   (V_DOT2_F32_BF16, VOP3P)
__device__ __forceinline__ float dot2bf(unsigned int a, unsigned int b, float c) {
  float d;
  asm("v_dot2_f32_bf16 %0, %1, %2, %3" : "=v"(d) : "v"(a), "v"(b), "v"(c));
  return d;
}
// RNE pack: two f32 -> dword {bf16(lo) low, bf16(hi) high}  (hardware RNE —
// removes r7's round-half-up bias, the source of its absmax 48)
__device__ __forceinline__ unsigned int pkbf(float lo, float hi) {
  unsigned int u;
  asm("v_cvt_pk_bf16_f32 %0, %1, %2" : "=v"(u) : "v"(lo), "v"(hi));
  return u;
}
__device__ __forceinline__ unsigned short to_bf16_rne(float x) {
  return (unsigned short)(pkbf(x, x) & 0xFFFFu);
}

// s + quad_perm(s): VALU-only cross-lane add within the 4-lane quad (q-group).
template <int CTRL>
__device__ __forceinline__ float dpp_qp_add(float s) {
  union { float f; int i; } a, r;
  a.f = s;
  r.i = __builtin_amdgcn_update_dpp(a.i, a.i, CTRL, 0xf, 0xf, false);
  return s + r.f;
}
#define QP_XOR1 0xB1   // quad_perm [1,0,3,2]
#define QP_XOR2 0x4E   // quad_perm [2,3,0,1]

__device__ __forceinline__ float bf16lo(unsigned int d) {
  union { unsigned int u; float f; } v; v.u = d << 16;        return v.f;
}
__device__ __forceinline__ float bf16hi(unsigned int d) {
  union { unsigned int u; float f; } v; v.u = d & 0xFFFF0000u; return v.f;
}

// ============================================================================
// r7 champion structure (229 us), unchanged: one block per chain; 256 threads:
// q = tid&3 (prev-quarter, 32 states), nb = tid>>2 -> next-states nb, nb+64.
// Linear-space recursion a_new[n] = exp(feat[n]) * sum_p E[n,p] a[p].
// E = exp(trans) as packed bf16 pairs (16 dwords/row, 32/thread, VGPR-resident
// via waves_per_eu(2,2) -- r13-proven fix for the accvgpr-stash tax).
// Alpha in LDS as bf16 pairs, double-buffered; 4 x ds_read_b128 per thread.
// Renormalize block max -> 1 every 4 steps (bf16 exponent range == fp32:
// 4-step growth ~1e24 << 3e38). All f32->bf16 via hardware RNE (cvt_pk).
// ============================================================================
__global__ __attribute__((amdgpu_flat_work_group_size(NTHR, NTHR),
                          amdgpu_waves_per_eu(2, 2)))
void crf_v14(
    const float* __restrict__ feats,   // [B,T,K]
    const int*   __restrict__ tags,    // [B,T]
    const float* __restrict__ trans,   // [K,K]  trans[next, prev]
    float* __restrict__ part)          // [B]
{
  const int b   = blockIdx.x;
  const int tid = threadIdx.x;
  const int q   = tid & 3;
  const int nb  = tid >> 2;       // 0..63
  const int w   = tid >> 6;       // wave id 0..3

  __shared__ __align__(16) unsigned int aW[2][Kk/2];  // bf16 pairs: word d = rows 2d,2d+1
  __shared__ float red[4];

  // ---- E rows, packed bf16 pairs (RNE): E0[j] = {E[nb][32q+2j], E[nb][32q+2j+1]} ----
  unsigned int E0[16], E1[16];
  {
    const float* t0 = trans + (size_t)nb * Kk + q * PW;
    const float* t1 = trans + (size_t)(nb + 64) * Kk + q * PW;
    #pragma unroll
    for (int j = 0; j < 16; ++j) {
      float2 v0 = *(const float2*)(t0 + 2*j);
      float2 v1 = *(const float2*)(t1 + 2*j);
      E0[j] = pkbf(fexp2(v0.x * LOG2E), fexp2(v0.y * LOG2E));
      E1[j] = pkbf(fexp2(v1.x * LOG2E), fexp2(v1.y * LOG2E));
    }
  }
  #pragma unroll
  for (int j = 0; j < 16; ++j)
    asm volatile("" : "+v"(E0[j]), "+v"(E1[j]));   // keep resident, no remat

  // ---- alpha0: 1.0 at START (row 126 -> word 63 lo half), else 0 ----
  if (tid < Kk/2) aW[0][tid] = (tid == 63) ? 0x00003F80u : 0u;
  __syncthreads();

  const float* fb = feats + (size_t)b * Tt * Kk;
  float C2 = 0.0f;                 // renorm offset, log2 units (uniform)
  float f0 = fb[nb] * LOG2E, f1 = fb[nb + 64] * LOG2E;

  for (int t = 0; t < Tt; ++t) {
    const int cur = t & 1;
    float f0n = 0.f, f1n = 0.f;
    if (t + 1 < Tt) {
      f0n = fb[(size_t)(t + 1) * Kk + nb] * LOG2E;
      f1n = fb[(size_t)(t + 1) * Kk + nb + 64] * LOG2E;
    }

    // 4 b128 reads = this thread's 32 prev states (bf16 pairs, 16 dwords)
    const uint4* ap = (const uint4*)&aW[cur][q * 16];
    uint4 av[4];
    #pragma unroll
    for (int j4 = 0; j4 < 4; ++j4) av[j4] = ap[j4];

    // 16 dot2 per row, 4 accumulator chains per row
    float a0=0.f,a1=0.f,a2=0.f,a3=0.f, c0=0.f,c1=0.f,c2=0.f,c3=0.f;
    #pragma unroll
    for (int j4 = 0; j4 < 4; ++j4) {
      a0 = dot2bf(E0[4*j4+0], av[j4].x, a0);
      a1 = dot2bf(E0[4*j4+1], av[j4].y, a1);
      a2 = dot2bf(E0[4*j4+2], av[j4].z, a2);
      a3 = dot2bf(E0[4*j4+3], av[j4].w, a3);
      c0 = dot2bf(E1[4*j4+0], av[j4].x, c0);
      c1 = dot2bf(E1[4*j4+1], av[j4].y, c1);
      c2 = dot2bf(E1[4*j4+2], av[j4].z, c2);
      c3 = dot2bf(E1[4*j4+3], av[j4].w, c3);
    }
    float s0 = (a0 + a1) + (a2 + a3);
    float s1 = (c0 + c1) + (c2 + c3);
    s0 = dpp_qp_add<QP_XOR1>(s0);
    s0 = dpp_qp_add<QP_XOR2>(s0);
    s1 = dpp_qp_add<QP_XOR1>(s1);
    s1 = dpp_qp_add<QP_XOR2>(s1);
    float y0 = fexp2(f0) * s0;     // full sums in all quad lanes
    float y1 = fexp2(f1) * s1;

    if ((t & 3) == 3) {            // renormalize block max -> 1 (4-step amortized)
      float m = fmaxf(y0, y1);     // quad-uniform; reduce across nb groups
      m = fmaxf(m, __shfl_xor(m, 4, 64));
      m = fmaxf(m, __shfl_xor(m, 8, 64));
      m = fmaxf(m, __shfl_xor(m, 16, 64));
      m = fmaxf(m, __shfl_xor(m, 32, 64));
      if ((tid & 63) == 0) red[w] = m;
      __syncthreads();
      m = fmaxf(fmaxf(red[0], red[1]), fmaxf(red[2], red[3]));
      C2 += flog2(m);
      const float inv = frcp(m);
      y0 *= inv; y1 *= inv;
    }

    const int nxt = cur ^ 1;
    unsigned short* aH = (unsigned short*)&aW[nxt][0];
    if (q == 0) aH[nb]      = to_bf16_rne(y0);
    if (q == 1) aH[nb + 64] = to_bf16_rne(y1);
    __syncthreads();
    f0 = f0n; f1 = f1n;
  }

  // ---- forward score: ln( sum_n a[n] * exp(T[STOP,n]) ) + offset ----
  float v = 0.0f;
  if (tid < Kk) {
    const unsigned int d = aW[0][tid >> 1];
    const float an = (tid & 1) ? bf16hi(d) : bf16lo(d);
    v = an * fexp2(trans[(size_t)NSTOP * Kk + tid] * LOG2E);
  }
  #pragma unroll
  for (int off = 32; off >= 1; off >>= 1) v += __shfl_xor(v, off, 64);
  if ((tid & 63) == 0) red[w] = v;
  __syncthreads();
  const float S = (red[0] + red[1]) + (red[2] + red[3]);
  const float fwd = LN2 * (C2 + flog2(S));

  // ---- gold path score (2 timesteps per thread) ----
  __syncthreads();                   // red reuse guard
  const int* tg = tags + (size_t)b * Tt;
  float g = 0.0f;
  #pragma unroll
  for (int k2 = 0; k2 < Tt / NTHR; ++k2) {
    const int tt   = tid + k2 * NTHR;
    const int curt = tg[tt];
    const int prv  = (tt == 0) ? NSTART : tg[tt - 1];
    g += trans[(size_t)curt * Kk + prv] + fb[(size_t)tt * Kk + curt];
  }
  if (tid == 0) g += trans[(size_t)NSTOP * Kk + tg[Tt - 1]];
  #pragma unroll
  for (int off = 32; off >= 1; off >>= 1) g += __shfl_xor(g, off, 64);
  if ((tid & 63) == 0) red[w] = g;
  __syncthreads();
  const float gold = (red[0] + red[1]) + (red[2] + red[3]);

  if (tid == 0) part[b] = fwd - gold;
}

__global__ __launch_bounds__(256) void reduce_mean_kernel(
    const float* __restrict__ part, float* __restrict__ out)
{
  __shared__ float buf[4];
  const int tid = threadIdx.x;
  float v = part[tid] + part[tid + 256];
  #pragma unroll
  for (int off = 32; off >= 1; off >>= 1) v += __shfl_xor(v, off, 64);
  if ((tid & 63) == 0) buf[tid >> 6] = v;
  __syncthreads();
  if (tid == 0)
    out[0] = (buf[0] + buf[1] + buf[2] + buf[3]) * (1.0f / (float)Bb);
}

extern "C" void kernel_launch(void* const* d_in, const int* in_sizes, int n_in,
                              void* d_out, int out_size, void* d_ws, size_t ws_size,
                              hipStream_t stream) {
  const float* feats = (const float*)d_in[0];
  const int*   tags  = (const int*)d_in[1];
  const float* trans = (const float*)d_in[2];
  float* part = (float*)d_ws;

  crf_v14<<<dim3(Bb), dim3(NTHR), 0, stream>>>(feats, tags, trans, part);
  reduce_mean_kernel<<<dim3(1), dim3(256), 0, stream>>>(part, (float*)d_out);
}